// Round 4
// baseline (774.283 us; speedup 1.0000x reference)
//
#include <hip/hip_runtime.h>

// GatedLinearAttention, fp32 I/O, split-bf16 MFMA GEMMs.
// B=2, S=8192, H=1024, NH=16, T=16384 tokens.
//
// fp32 x = hi + lo (bf16);  A@B ~= Ahi@Bhi + Alo@Bhi + Ahi@Blo  == one K=3072
// GEMM with phased base offsets (A: hi|lo|hi, B: hi|hi|lo).
//
// This round: B operand bypasses LDS (read direct global->VGPR from the
// L2-resident 4 MB weight panel); A stays LDS-staged (4x wave reuse).
// HARDENED vs r3: sched_barrier(0) pins VMEM issue order so the manual
// vmcnt(4) FIFO accounting is scheduler-proof:
//   - prologue: [STG_A x4] | SB | [GL_B x4] | SB | vmcnt(4)  -> drains A.
//   - per tile: region1 = {GL_B(bf1), STG_A(t+1) x4}, SB at p2 start,
//     region2 = {GL_B(bf0-next), MFMAs, vmcnt(4)}. For any within-region
//     order, at vmcnt(4) the outstanding set is [A x4 (older), bf0-next x4];
//     the wait drains exactly the A staging. Cross-region motion impossible.
//   - ONE barrier per K-tile (A-only staging; reads provably returned
//     before the FENCE'd barrier via compiler lgkm waits on consuming MFMAs).
//   - B-load lead ~2 phases >> L2 latency; A lead = 1 tile.
//   - chunk-XOR LDS swizzle for A verbatim (0 conflicts measured).
// Tail prefetches (tile 48) land in-bounds of workspace, never consumed.
//
// Pipeline (ws ~150 MB): split_w, split_hidden -> Hs
//   K: kb = elu(h@Wk)+1 [EPI 0]; ksum; Q: sc[t][h] epilogue [EPI 1];
//   V: over kb [EPI 2]; token_lite (z=v*sc, LN -> zn bf16 hi|lo in place);
//   G: gate (zn*gamma+beta)*silu(g) in place [EPI 3]; O: Zs@Wo [EPI 2].
// Fallback (ws < 150 MB): round-4 proven on-the-fly-split path.

typedef unsigned short ushort_t;
typedef unsigned int uint_t;

using short8  = __attribute__((ext_vector_type(8))) short;
using floatx4 = __attribute__((ext_vector_type(4))) float;

#define HDIM  1024
#define T_TOK 16384
#define KSPLIT 3072

__device__ __forceinline__ ushort_t f2bf(float f) {
    uint_t u = __builtin_bit_cast(uint_t, f);
    u = (u + 0x7fff + ((u >> 16) & 1)) >> 16;  // RNE
    return (ushort_t)u;
}
__device__ __forceinline__ float bf2f(ushort_t h) {
    uint_t u = ((uint_t)h) << 16;
    return __builtin_bit_cast(float, u);
}
__device__ __forceinline__ void split2(float f, ushort_t& hi, ushort_t& lo) {
    hi = f2bf(f);
    lo = f2bf(f - bf2f(hi));
}
__device__ __forceinline__ void gload_lds16(const ushort_t* g, ushort_t* l) {
    __builtin_amdgcn_global_load_lds(
        (const __attribute__((address_space(1))) void*)g,
        (__attribute__((address_space(3))) void*)l, 16, 0, 0);
}

// ---------------- weight split+transpose: W[k][n] fp32 -> WT2[n][2048] bf16 hi|lo ----------------
__global__ void split_w(const float* __restrict__ W0, const float* __restrict__ W1,
                        const float* __restrict__ W2, const float* __restrict__ W3,
                        const float* __restrict__ W4, ushort_t* __restrict__ WT2) {
    __shared__ float tile[32][33];
    const int z = blockIdx.z;
    const float* W = (z == 0) ? W0 : (z == 1) ? W1 : (z == 2) ? W2 : (z == 3) ? W3 : W4;
    ushort_t* dst = WT2 + (size_t)z * HDIM * 2048;
    const int n0 = blockIdx.x * 32, k0 = blockIdx.y * 32;
    const int tx = threadIdx.x & 31, ty0 = threadIdx.x >> 5;
#pragma unroll
    for (int s = 0; s < 4; ++s) {
        int ty = ty0 + 8 * s;
        tile[ty][tx] = W[(size_t)(k0 + ty) * HDIM + n0 + tx];
    }
    __syncthreads();
#pragma unroll
    for (int s = 0; s < 4; ++s) {
        int ty = ty0 + 8 * s;
        float v = tile[tx][ty];
        ushort_t hi, lo;
        split2(v, hi, lo);
        dst[(size_t)(n0 + ty) * 2048 + k0 + tx] = hi;
        dst[(size_t)(n0 + ty) * 2048 + 1024 + k0 + tx] = lo;
    }
}

// ---------------- hidden split: h[t][1024] fp32 -> Hs[t][2048] bf16 hi|lo ----------------
__global__ __launch_bounds__(256)
void split_hidden(const float* __restrict__ h, ushort_t* __restrict__ Hs) {
    const int t = blockIdx.x;
    const int c = threadIdx.x;
    const float4 x = ((const float4*)(h + (size_t)t * HDIM))[c];
    ushort_t hi[4], lo[4];
    split2(x.x, hi[0], lo[0]); split2(x.y, hi[1], lo[1]);
    split2(x.z, hi[2], lo[2]); split2(x.w, hi[3], lo[3]);
    ushort_t* row = Hs + (size_t)t * 2048;
    uint2 hp, lp;
    hp.x = (uint_t)hi[0] | ((uint_t)hi[1] << 16);
    hp.y = (uint_t)hi[2] | ((uint_t)hi[3] << 16);
    lp.x = (uint_t)lo[0] | ((uint_t)lo[1] << 16);
    lp.y = (uint_t)lo[2] | ((uint_t)lo[3] << 16);
    *(uint2*)(row + c * 4) = hp;
    *(uint2*)(row + 1024 + c * 4) = lp;
}

// ---------------- 256x256 split GEMM: A via LDS, B direct global->reg ----------------
// EPI 0: D = elu(A@B)+1 fp32     EPI 1: sc-reduction (q; uses kf,ksum,scbuf)
// EPI 2: D = A@B fp32            EPI 3: gate (zn*gamma+beta)*silu(g) RMW on zbuf

#define FENCE() asm volatile("" ::: "memory")
#define VMW4()  asm volatile("s_waitcnt vmcnt(4)" ::: "memory")
#define SB()    __builtin_amdgcn_sched_barrier(0)

#define STG_A(t, h, bsel) do { \
    const int ka_ = ((t) * 64 >= 2048) ? ((t) * 64 - 2048) : ((t) * 64); \
    gload_lds16(Ag + (size_t)((h) * 128) * 2048 + ka_, \
                &As[(bsel) * 16384 + ((h) * 128 + w * 16) * 64]); \
    gload_lds16(Ag + (size_t)((h) * 128 + 8) * 2048 + ka_, \
                &As[(bsel) * 16384 + ((h) * 128 + w * 16 + 8) * 64]); \
  } while (0)

// B fragments direct from global (L2-resident weight panel), kc = k-chunk 0/1.
#define GL_B(dst, t, kc) do { \
    const int kb_ = ((t) * 64 >= 1024) ? ((t) * 64 - 1024) : ((t) * 64); \
    _Pragma("unroll") \
    for (int _j = 0; _j < 4; ++_j) \
        dst[_j] = *(const short8*)(Bgr + (size_t)(_j * 16) * 2048 + kb_ + (kc) * 32); \
  } while (0)

// af fragment block mb (0 or 4): rows (wm*128 + (mb+i)*16 + lrow); kc chunk.
#define RD_A(dst, bsel, mb, kc) do { \
    const ushort_t* _pa = ((kc) ? Ar1 : Ar0) + (bsel) * 16384; \
    _Pragma("unroll") \
    for (int _i = 0; _i < 4; ++_i) \
        dst[_i] = *(const short8*)(_pa + ((mb) + _i) * 1024); \
  } while (0)

// 16 independent MFMAs: acc[mb..mb+3][0..3] += a[i] x b[j]  (one k-chunk)
#define MMX(mb, a, b) do { \
    __builtin_amdgcn_s_setprio(1); \
    _Pragma("unroll") \
    for (int _i = 0; _i < 4; ++_i) \
    _Pragma("unroll") \
    for (int _j = 0; _j < 4; ++_j) \
        acc[(mb) + _i][_j] = __builtin_amdgcn_mfma_f32_16x16x32_bf16( \
            a[_i], b[_j], acc[(mb) + _i][_j], 0, 0, 0); \
    __builtin_amdgcn_s_setprio(0); \
  } while (0)

// One K-tile. Entry invariant: buf[bsel] holds A(t); afA = A(t)[m0-3][k0]
// read-issued; bf0 = B(t)[k0] load-issued (compiler auto-waits).
#define TILE(t, bsel) do { \
    /* region 1 (p0+p1): B(t,k1) + A(t+1) staging; k0 MFMAs */ \
    GL_B(bf1, (t), 1); \
    RD_A(afB, bsel, 4, 0); \
    STG_A((t) + 1, 0, (bsel) ^ 1); \
    MMX(0, afA, bf0); \
    RD_A(afA, bsel, 0, 1); \
    STG_A((t) + 1, 1, (bsel) ^ 1); \
    MMX(4, afB, bf0); \
    /* region split: pins A-staging above, bf0-next below (vmcnt FIFO) */ \
    SB(); \
    /* region 2 (p2+p3): B(t+1,k0); k1 MFMAs; boundary wait+barrier */ \
    GL_B(bf0, (t) + 1, 0); \
    RD_A(afB, bsel, 4, 1); \
    MMX(0, afA, bf1); \
    MMX(4, afB, bf1); \
    VMW4(); \
    FENCE(); __builtin_amdgcn_s_barrier(); FENCE(); \
    SB(); \
    RD_A(afA, (bsel) ^ 1, 0, 0); \
  } while (0)

template <int EPI>
__global__ __launch_bounds__(512, 2)
void gemm256(const ushort_t* __restrict__ A, const ushort_t* __restrict__ Bw,
             float* __restrict__ D, const float* __restrict__ kf,
             const float* __restrict__ ksum, float* __restrict__ scbuf,
             ushort_t* __restrict__ zbuf, const float* __restrict__ gamma,
             const float* __restrict__ beta) {
    __shared__ ushort_t As[2 * 256 * 64];   // 64 KiB (A only; B in registers)
    const int tid = threadIdx.x;
    const int bx = blockIdx.x, by = blockIdx.y;
    const int w = tid >> 6, lane = tid & 63;
    const int wm = w & 1, wn = w >> 1;          // 2 M-waves x 4 N-waves
    const int lrow = lane & 15, lq = lane >> 4;

    // A staging: wave w covers rows h*128 + w*16 + {0..15}; lane covers row
    // +(lane>>3), swizzled 16B chunk ((lane&7) ^ (row&7)).
    const int srow = lane >> 3;
    const int scol = ((lane & 7) ^ srow) * 8;
    const ushort_t* Ag = A + (size_t)(bx * 256 + w * 16 + srow) * 2048 + scol;
    // B fragment base: col (by*256 + wn*64 + lrow), k-offset lq*8.
    const ushort_t* Bgr = Bw + (size_t)(by * 256 + wn * 64 + lrow) * 2048 + lq * 8;

    // A read-side unswizzle bases (kk=0 chunk c0, kk=32 chunk c1)
    const int c0 = (lq ^ (lrow & 7)) * 8;
    const int c1 = ((lq + 4) ^ (lrow & 7)) * 8;
    const ushort_t* Ar0 = As + (wm * 128 + lrow) * 64 + c0;
    const ushort_t* Ar1 = As + (wm * 128 + lrow) * 64 + c1;

    floatx4 acc[8][4] = {};
    short8 afA[4], afB[4], bf0[4], bf1[4];

    // prologue: stage A(0) | SB | load B(0,k0) | SB | vmcnt(4) -> A(0) landed.
    STG_A(0, 0, 0); STG_A(0, 1, 0);
    SB();
    GL_B(bf0, 0, 0);
    SB();
    VMW4();
    FENCE(); __builtin_amdgcn_s_barrier(); FENCE();
    SB();
    RD_A(afA, 0, 0, 0);

#pragma unroll 1
    for (int t = 0; t < 48; t += 2) {
        TILE(t, 0);
        TILE(t + 1, 1);
    }

    const int rowbase = bx * 256 + wm * 128 + lq * 4;
    const int colbase = by * 256 + wn * 64 + lrow;

    if constexpr (EPI == 0 || EPI == 2) {
#pragma unroll
        for (int i = 0; i < 8; ++i)
#pragma unroll
            for (int j = 0; j < 4; ++j) {
                const int col = colbase + j * 16;
#pragma unroll
                for (int r = 0; r < 4; ++r) {
                    const int row = rowbase + i * 16 + r;
                    float val = acc[i][j][r];
                    if (EPI == 0) val = (val > 0.0f) ? (val + 1.0f) : (expm1f(val) + 1.0f);
                    D[(size_t)row * HDIM + col] = val;
                }
            }
    } else if constexpr (EPI == 1) {
        // q epilogue: head h = by*4 + wn spans cols [h*64, h*64+64)
        const int b = bx >> 5;  // uniform per block (row/8192)
        float ksv[4];
#pragma unroll
        for (int j = 0; j < 4; ++j) ksv[j] = ksum[b * HDIM + colbase + j * 16];
        const int h = by * 4 + wn;
#pragma unroll
        for (int i = 0; i < 8; ++i)
#pragma unroll
            for (int r = 0; r < 4; ++r) {
                const int row = rowbase + i * 16 + r;
                float qk = 0.f, nm = 0.f;
#pragma unroll
                for (int j = 0; j < 4; ++j) {
                    float qv = acc[i][j][r];
                    qv = (qv > 0.0f) ? (qv + 1.0f) : (expm1f(qv) + 1.0f);
                    const float kv = kf[(size_t)row * HDIM + colbase + j * 16];
                    qk += qv * kv;
                    nm += qv * ksv[j];
                }
#pragma unroll
                for (int off = 1; off < 16; off <<= 1) {
                    qk += __shfl_xor(qk, off, 64);
                    nm += __shfl_xor(nm, off, 64);
                }
                if (lrow == 0) scbuf[row * 16 + h] = qk / (nm + 1e-6f);
            }
    } else {  // EPI == 3: gate zn' = (zn*gamma+beta)*silu(g), in-place RMW
#pragma unroll
        for (int i = 0; i < 8; ++i)
#pragma unroll
            for (int j = 0; j < 4; ++j) {
                const int col = colbase + j * 16;
                const float gam = gamma[col], bet = beta[col];
#pragma unroll
                for (int r = 0; r < 4; ++r) {
                    const int row = rowbase + i * 16 + r;
                    ushort_t* zr = zbuf + (size_t)row * 2048;
                    const float zn = bf2f(zr[col]) + bf2f(zr[1024 + col]);
                    const float g = acc[i][j][r];
                    const float sg = g / (1.0f + expf(-g));
                    ushort_t hi, lo;
                    split2((zn * gam + bet) * sg, hi, lo);
                    zr[col] = hi;
                    zr[1024 + col] = lo;
                }
            }
    }
}

// ---------------- swizzled m97-style 128x128 split GEMM (fallback O-GEMM) ----------------
template <int EPI>
__global__ __launch_bounds__(256)
void gemm_swz(const ushort_t* __restrict__ A, const ushort_t* __restrict__ Bw,
              float* __restrict__ D, const float* __restrict__ kf,
              const float* __restrict__ ksum, float* __restrict__ scbuf,
              ushort_t* __restrict__ zbuf) {
    __shared__ ushort_t As[128 * 64];
    __shared__ ushort_t Bs[128 * 64];
    const int tid = threadIdx.x;
    const int bx = blockIdx.x, by = blockIdx.y;
    const int w = tid >> 6, lane = tid & 63;
    const int wm = w & 1, wn = w >> 1;
    const int lrow = lane & 15, lq = lane >> 4;

    const int srow = lane >> 3;
    const int scol = ((lane & 7) ^ srow) * 8;
    const ushort_t* Ag = A + (size_t)(bx * 128 + w * 32 + srow) * 2048 + scol;
    const ushort_t* Bg = Bw + (size_t)(by * 128 + w * 32 + srow) * 2048 + scol;

    floatx4 acc[4][4] = {};

    for (int k0 = 0; k0 < KSPLIT; k0 += 64) {
        const int ka = k0 - ((k0 >= 2048) ? 2048 : 0);
        const int kb = k0 - ((k0 >= 1024) ? 1024 : 0);
        __syncthreads();
#pragma unroll
        for (int n = 0; n < 4; ++n) {
            gload_lds16(Ag + (size_t)(n * 8) * 2048 + ka, &As[(w * 32 + n * 8) * 64]);
            gload_lds16(Bg + (size_t)(n * 8) * 2048 + kb, &Bs[(w * 32 + n * 8) * 64]);
        }
        __syncthreads();
#pragma unroll
        for (int kk = 0; kk < 64; kk += 32) {
            short8 af[4], bf[4];
#pragma unroll
            for (int i = 0; i < 4; ++i) {
                const int c = (((kk >> 3) + lq) ^ (lrow & 7)) * 8;
                af[i] = *(const short8*)&As[(wm * 64 + i * 16 + lrow) * 64 + c];
            }
#pragma unroll
            for (int j = 0; j < 4; ++j) {
                const int c = (((kk >> 3) + lq) ^ (lrow & 7)) * 8;
                bf[j] = *(const short8*)&Bs[(wn * 64 + j * 16 + lrow) * 64 + c];
            }
#pragma unroll
            for (int i = 0; i < 4; ++i)
#pragma unroll
                for (int j = 0; j < 4; ++j)
                    acc[i][j] = __builtin_amdgcn_mfma_f32_16x16x32_bf16(af[i], bf[j], acc[i][j], 0, 0, 0);
        }
    }

    const int rowbase = bx * 128 + wm * 64 + lq * 4;
    const int colbase = by * 128 + wn * 64 + lrow;
#pragma unroll
    for (int i = 0; i < 4; ++i)
#pragma unroll
        for (int j = 0; j < 4; ++j) {
            const int col = colbase + j * 16;
#pragma unroll
            for (int r = 0; r < 4; ++r) {
                const int row = rowbase + i * 16 + r;
                float val = acc[i][j][r];
                if (EPI == 0) val = (val > 0.0f) ? (val + 1.0f) : (expm1f(val) + 1.0f);
                D[(size_t)row * HDIM + col] = val;
            }
        }
}

// ---------------- ksum: deterministic two-stage ----------------
__global__ void ksum_partial(const float* __restrict__ kf, float* __restrict__ partial) {
    const int rg = blockIdx.x;
    const int tid = threadIdx.x;
    const float4* p = (const float4*)(kf + (size_t)rg * 64 * HDIM) + tid;
    float4 s = {0.f, 0.f, 0.f, 0.f};
    for (int r = 0; r < 64; ++r) {
        float4 x = p[(size_t)r * (HDIM / 4)];
        s.x += x.x; s.y += x.y; s.z += x.z; s.w += x.w;
    }
    ((float4*)(partial + (size_t)rg * HDIM))[tid] = s;
}
__global__ void ksum_reduce(const float* __restrict__ partial, float* __restrict__ ksum) {
    const int b = blockIdx.y;
    const int c = blockIdx.x * 256 + threadIdx.x;
    float s = 0.f;
    const float* p = partial + (size_t)b * 128 * HDIM + c;
    for (int rg = 0; rg < 128; ++rg) s += p[(size_t)rg * HDIM];
    ksum[b * HDIM + c] = s;
}

// ---------------- token-lite: z = v*sc, LayerNorm -> zn bf16 hi|lo in place ----------------
__global__ __launch_bounds__(256)
void token_lite(float* vz, const float* __restrict__ scbuf) {
    const int t = blockIdx.x;
    const int tid = threadIdx.x;
    const float4 v = ((const float4*)(vz + (size_t)t * HDIM))[tid];
    const float sc = scbuf[t * 16 + (tid >> 4)];
    float z[4] = {v.x * sc, v.y * sc, v.z * sc, v.w * sc};

    __shared__ float red[8];
    const int wv = tid >> 6, lane = tid & 63;

    float s1 = z[0] + z[1] + z[2] + z[3];
#pragma unroll
    for (int off = 1; off < 64; off <<= 1) s1 += __shfl_xor(s1, off, 64);
    if (lane == 0) red[wv] = s1;
    __syncthreads();
    const float mu = (red[0] + red[1] + red[2] + red[3]) * (1.0f / 1024.0f);

    float d[4] = {z[0] - mu, z[1] - mu, z[2] - mu, z[3] - mu};
    float s2 = d[0] * d[0] + d[1] * d[1] + d[2] * d[2] + d[3] * d[3];
#pragma unroll
    for (int off = 1; off < 64; off <<= 1) s2 += __shfl_xor(s2, off, 64);
    __syncthreads();
    if (lane == 0) red[4 + wv] = s2;
    __syncthreads();
    const float var = (red[4] + red[5] + red[6] + red[7]) * (1.0f / 1024.0f);
    const float rstd = rsqrtf(var + 1e-5f);

    ushort_t* zrow = (ushort_t*)(vz + (size_t)t * HDIM);
    ushort_t hi[4], lo[4];
#pragma unroll
    for (int c = 0; c < 4; ++c) split2(d[c] * rstd, hi[c], lo[c]);
    uint2 hp, lp;
    hp.x = (uint_t)hi[0] | ((uint_t)hi[1] << 16);
    hp.y = (uint_t)hi[2] | ((uint_t)hi[3] << 16);
    lp.x = (uint_t)lo[0] | ((uint_t)lo[1] << 16);
    lp.y = (uint_t)lo[2] | ((uint_t)lo[3] << 16);
    *(uint2*)(zrow + tid * 4) = hp;
    *(uint2*)(zrow + 1024 + tid * 4) = lp;
}

// ---------------- fallback (ws < 150 MB): round-4 proven on-the-fly-split path ----------------
template <int VAR>
__global__ __launch_bounds__(256, 2)
void gemm_split(const float* __restrict__ A,
                const ushort_t* __restrict__ B0, const ushort_t* __restrict__ B1,
                const ushort_t* __restrict__ B2,
                float* __restrict__ D0, float* __restrict__ D1, float* __restrict__ D2,
                int K) {
    __shared__ ushort_t Ah[128 * 72];
    __shared__ ushort_t Al[128 * 72];
    __shared__ ushort_t Bh[128 * 72];
    __shared__ ushort_t Bl[128 * 72];
    const int tid = threadIdx.x;
    const int bx = blockIdx.x, by = blockIdx.y;
    const ushort_t* Bt;
    float* D;
    int n0;
    bool act;
    if (VAR == 1) {
        const int wsel = by >> 3;
        Bt = (wsel == 0) ? B0 : (wsel == 1) ? B1 : B2;
        D = (wsel == 0) ? D0 : (wsel == 1) ? D1 : D2;
        n0 = (by & 7) * 128;
        act = (wsel == 0);
    } else {
        Bt = B0; D = D0; n0 = by * 128; act = true;
    }
    const int w = tid >> 6, lane = tid & 63;
    const int wm = w & 1, wn = w >> 1;
    const int lrow = lane & 15, lq = lane >> 4;
    const int srow = tid >> 1;
    const int shalf = (tid & 1) * 32;
    const float* Arow = A + (size_t)(bx * 128 + srow) * K;
    const ushort_t* Brow = Bt + (size_t)(n0 + srow) * 2048;
    floatx4 acc[4][4] = {};
    for (int k0 = 0; k0 < K; k0 += 64) {
        float4 afr[8];
        uint4 bhr[4], blr[4];
#pragma unroll
        for (int g = 0; g < 4; ++g) {
            afr[2 * g]     = *(const float4*)(Arow + k0 + shalf + g * 8);
            afr[2 * g + 1] = *(const float4*)(Arow + k0 + shalf + g * 8 + 4);
            bhr[g] = *(const uint4*)(Brow + k0 + shalf + g * 8);
            blr[g] = *(const uint4*)(Brow + 1024 + k0 + shalf + g * 8);
        }
        __syncthreads();
#pragma unroll
        for (int g = 0; g < 4; ++g) {
            ushort_t h[8], l[8];
            const float4 f0 = afr[2 * g], f1 = afr[2 * g + 1];
            split2(f0.x, h[0], l[0]); split2(f0.y, h[1], l[1]);
            split2(f0.z, h[2], l[2]); split2(f0.w, h[3], l[3]);
            split2(f1.x, h[4], l[4]); split2(f1.y, h[5], l[5]);
            split2(f1.z, h[6], l[6]); split2(f1.w, h[7], l[7]);
            uint4 hp, lp;
            hp.x = (uint_t)h[0] | ((uint_t)h[1] << 16);
            hp.y = (uint_t)h[2] | ((uint_t)h[3] << 16);
            hp.z = (uint_t)h[4] | ((uint_t)h[5] << 16);
            hp.w = (uint_t)h[6] | ((uint_t)h[7] << 16);
            lp.x = (uint_t)l[0] | ((uint_t)l[1] << 16);
            lp.y = (uint_t)l[2] | ((uint_t)l[3] << 16);
            lp.z = (uint_t)l[4] | ((uint_t)l[5] << 16);
            lp.w = (uint_t)l[6] | ((uint_t)l[7] << 16);
            *(uint4*)&Ah[srow * 72 + shalf + g * 8] = hp;
            *(uint4*)&Al[srow * 72 + shalf + g * 8] = lp;
            *(uint4*)&Bh[srow * 72 + shalf + g * 8] = bhr[g];
            *(uint4*)&Bl[srow * 72 + shalf + g * 8] = blr[g];
        }
        __syncthreads();
#pragma unroll
        for (int kk = 0; kk < 64; kk += 32) {
            short8 ah[4], bh[4], xl[4];
#pragma unroll
            for (int i = 0; i < 4; ++i)
                ah[i] = *(const short8*)&Ah[(wm * 64 + i * 16 + lrow) * 72 + kk + lq * 8];
#pragma unroll
            for (int j = 0; j < 4; ++j)
                bh[j] = *(const short8*)&Bh[(wn * 64 + j * 16 + lrow) * 72 + kk + lq * 8];
#pragma unroll
            for (int i = 0; i < 4; ++i)
#pragma unroll
                for (int j = 0; j < 4; ++j)
                    acc[i][j] = __builtin_amdgcn_mfma_f32_16x16x32_bf16(ah[i], bh[j], acc[i][j], 0, 0, 0);
#pragma unroll
            for (int i = 0; i < 4; ++i)
                xl[i] = *(const short8*)&Al[(wm * 64 + i * 16 + lrow) * 72 + kk + lq * 8];
#pragma unroll
            for (int i = 0; i < 4; ++i)
#pragma unroll
                for (int j = 0; j < 4; ++j)
                    acc[i][j] = __builtin_amdgcn_mfma_f32_16x16x32_bf16(xl[i], bh[j], acc[i][j], 0, 0, 0);
#pragma unroll
            for (int j = 0; j < 4; ++j)
                xl[j] = *(const short8*)&Bl[(wn * 64 + j * 16 + lrow) * 72 + kk + lq * 8];
#pragma unroll
            for (int i = 0; i < 4; ++i)
#pragma unroll
                for (int j = 0; j < 4; ++j)
                    acc[i][j] = __builtin_amdgcn_mfma_f32_16x16x32_bf16(ah[i], xl[j], acc[i][j], 0, 0, 0);
        }
    }
    const int rowbase = bx * 128 + wm * 64 + lq * 4;
    const int colbase = n0 + wn * 64 + lrow;
#pragma unroll
    for (int i = 0; i < 4; ++i)
#pragma unroll
        for (int j = 0; j < 4; ++j) {
            const int col = colbase + j * 16;
#pragma unroll
            for (int r = 0; r < 4; ++r) {
                const int row = rowbase + i * 16 + r;
                float val = acc[i][j][r];
                if (act) val = (val > 0.0f) ? (val + 1.0f) : (expm1f(val) + 1.0f);
                D[(size_t)row * HDIM + col] = val;
            }
        }
}

__global__ __launch_bounds__(256)
void token_f32(const float* __restrict__ qd, const float* __restrict__ vd,
               const float* __restrict__ gd, float* kz,
               const float* __restrict__ ksum,
               const float* __restrict__ gamma, const float* __restrict__ beta,
               int chunk_base) {
    const int tl = blockIdx.x;
    const int t = chunk_base + tl;
    const int b = t >> 13;
    const int tid = threadIdx.x;
    const float4 q = ((const float4*)(qd + (size_t)tl * HDIM))[tid];
    const float4 k = ((const float4*)(kz + (size_t)t * HDIM))[tid];
    const float4 v = ((const float4*)(vd + (size_t)tl * HDIM))[tid];
    const float4 ks = ((const float4*)(ksum + (size_t)b * HDIM))[tid];
    float qk = q.x * k.x + q.y * k.y + q.z * k.z + q.w * k.w;
    float nm = q.x * ks.x + q.y * ks.y + q.z * ks.z + q.w * ks.w;
#pragma unroll
    for (int off = 1; off < 16; off <<= 1) {
        qk += __shfl_xor(qk, off, 64);
        nm += __shfl_xor(nm, off, 64);
    }
    const float sc = qk / (nm + 1e-6f);
    float z[4] = {v.x * sc, v.y * sc, v.z * sc, v.w * sc};
    __shared__ float red[8];
    const int wv = tid >> 6, lane = tid & 63;
    float s1 = z[0] + z[1] + z[2] + z[3];
#pragma unroll
    for (int off = 1; off < 64; off <<= 1) s1 += __shfl_xor(s1, off, 64);
    if (lane == 0) red[wv] = s1;
    __syncthreads();
    const float mu = (red[0] + red[1] + red[2] + red[3]) * (1.0f / 1024.0f);
    float d[4] = {z[0] - mu, z[1] - mu, z[2] - mu, z[3] - mu};
    float s2 = d[0] * d[0] + d[1] * d[1] + d[2] * d[2] + d[3] * d[3];
#pragma unroll
    for (int off = 1; off < 64; off <<= 1) s2 += __shfl_xor(s2, off, 64);
    __syncthreads();
    if (lane == 0) red[4 + wv] = s2;
    __syncthreads();
    const float var = (red[4] + red[5] + red[6] + red[7]) * (1.0f / 1024.0f);
    const float rstd = rsqrtf(var + 1e-5f);
    const float4 gm = ((const float4*)gamma)[tid];
    const float4 bt = ((const float4*)beta)[tid];
    const float4 g = ((const float4*)(gd + (size_t)tl * HDIM))[tid];
    const float gv[4] = {g.x, g.y, g.z, g.w};
    const float gmv[4] = {gm.x, gm.y, gm.z, gm.w};
    const float btv[4] = {bt.x, bt.y, bt.z, bt.w};
    ushort_t hi[4], lo[4];
#pragma unroll
    for (int c = 0; c < 4; ++c) {
        const float zn = d[c] * rstd * gmv[c] + btv[c];
        const float sg = gv[c] / (1.0f + expf(-gv[c]));
        split2(zn * sg, hi[c], lo[c]);
    }
    ushort_t* zrow = (ushort_t*)(kz + (size_t)t * HDIM);
    uint2 hp, lp;
    hp.x = (uint_t)hi[0] | ((uint_t)hi[1] << 16);
    hp.y = (uint_t)hi[2] | ((uint_t)hi[3] << 16);
    lp.x = (uint_t)lo[0] | ((uint_t)lo[1] << 16);
    lp.y = (uint_t)lo[2] | ((uint_t)lo[3] << 16);
    *(uint2*)(zrow + tid * 4) = hp;
    *(uint2*)(zrow + 1024 + tid * 4) = lp;
}

// ---------------- launcher ----------------
extern "C" void kernel_launch(void* const* d_in, const int* in_sizes, int n_in,
                              void* d_out, int out_size, void* d_ws, size_t ws_size,
                              hipStream_t stream) {
    const float* hidden = (const float*)d_in[0];
    const float* Wq = (const float*)d_in[1];
    const float* Wk = (const float*)d_in[2];
    const float* Wv = (const float*)d_in[3];
    const float* Wg = (const float*)d_in[4];
    const float* Wo = (const float*)d_in[5];
    const float* gamma = (const float*)d_in[6];
    const float* beta = (const float*)d_in[7];

    char* w = (char*)d_ws;
    float* kb = (float*)w;            w += (size_t)67108864;   // k -> v -> zn -> Zs
    ushort_t* WT2 = (ushort_t*)w;     w += (size_t)20971520;   // 5 weights split [n][2048]
    float* partial = (float*)w;       w += (size_t)1048576;
    float* ksum = (float*)w;          w += (size_t)8192;
    float* scbuf = (float*)w;         w += (size_t)1048576;    // sc[t][16]
    const size_t base = (size_t)(w - (char*)d_ws);             // ~90.2 MB

    ushort_t* Wk2 = WT2;
    ushort_t* Wq2 = WT2 + (size_t)1 * HDIM * 2048;
    ushort_t* Wv2 = WT2 + (size_t)2 * HDIM * 2048;
    ushort_t* Wg2 = WT2 + (size_t)3 * HDIM * 2048;
    ushort_t* Wo2 = WT2 + (size_t)4 * HDIM * 2048;

    split_w<<<dim3(32, 32, 5), 256, 0, stream>>>(Wk, Wq, Wv, Wg, Wo, WT2);

    if (ws_size >= base + 67108864ull) {  // main path (measured ws >= ~173 MB)
        ushort_t* Hs = (ushort_t*)w;
        split_hidden<<<dim3(T_TOK), 256, 0, stream>>>(hidden, Hs);
        // K: kb = elu(h@Wk)+1
        gemm256<0><<<dim3(64, 4), 512, 0, stream>>>(Hs, Wk2, kb, nullptr, nullptr,
                                                    nullptr, nullptr, nullptr, nullptr);
        ksum_partial<<<dim3(256), 256, 0, stream>>>(kb, partial);
        ksum_reduce<<<dim3(4, 2), 256, 0, stream>>>(partial, ksum);
        // Q: epilogue-reduce sc[t][h]
        gemm256<1><<<dim3(64, 4), 512, 0, stream>>>(Hs, Wq2, nullptr, kb, ksum,
                                                    scbuf, nullptr, nullptr, nullptr);
        // V: v over kb (k dead)
        gemm256<2><<<dim3(64, 4), 512, 0, stream>>>(Hs, Wv2, kb, nullptr, nullptr,
                                                    nullptr, nullptr, nullptr, nullptr);
        // token-lite: z=v*sc, LN -> zn hi|lo in place
        token_lite<<<dim3(T_TOK), 256, 0, stream>>>(kb, scbuf);
        // G: gate (zn*gamma+beta)*silu(g) in place
        gemm256<3><<<dim3(64, 4), 512, 0, stream>>>(Hs, Wg2, nullptr, nullptr, nullptr,
                                                    nullptr, (ushort_t*)kb, gamma, beta);
        // O: out = Zs @ Wo
        gemm256<2><<<dim3(64, 4), 512, 0, stream>>>((const ushort_t*)kb, Wo2,
                                                    (float*)d_out, nullptr, nullptr,
                                                    nullptr, nullptr, nullptr, nullptr);
    } else {  // fallback: round-4 proven path (~110 MB)
        const int C = 2048;
        float* qc = (float*)w;
        float* vc = qc + (size_t)C * HDIM;
        float* gc = vc + (size_t)C * HDIM;
        gemm_split<0><<<dim3(128, 8), 256, 0, stream>>>(hidden, Wk2, nullptr, nullptr,
                                                        kb, nullptr, nullptr, HDIM);
        ksum_partial<<<dim3(256), 256, 0, stream>>>(kb, partial);
        ksum_reduce<<<dim3(4, 2), 256, 0, stream>>>(partial, ksum);
        for (int c = 0; c < 8; ++c) {
            const float* Ac = hidden + (size_t)c * C * HDIM;
            gemm_split<1><<<dim3(C / 128, 24), 256, 0, stream>>>(Ac, Wq2, Wv2, Wg2,
                                                                 qc, vc, gc, HDIM);
            token_f32<<<dim3(C), 256, 0, stream>>>(qc, vc, gc, kb, ksum,
                                                   gamma, beta, c * C);
        }
        gemm_swz<2><<<dim3(128, 8), 256, 0, stream>>>((const ushort_t*)kb, Wo2,
                                                      (float*)d_out, nullptr, nullptr,
                                                      nullptr, nullptr);
    }
}

// Round 5
// 663.895 us; speedup vs baseline: 1.1663x; 1.1663x over previous
//
#include <hip/hip_runtime.h>

// GatedLinearAttention, fp32 I/O, split-bf16 MFMA GEMMs.
// B=2, S=8192, H=1024, NH=16, T=16384 tokens.
//
// fp32 x = hi + lo (bf16);  A@B ~= Ahi@Bhi + Alo@Bhi + Ahi@Blo  == one K=3072
// GEMM with phased base offsets (A: hi|lo|hi, B: hi|hi|lo).
//
// ROUND 5: revert GEMM to the round-2 proven structure (best measured:
// 122 us/GEMM; r4's B-bypass regressed 16% -> reverted), plus one fusion:
//   - ksum folded into the K-GEMM epilogue: each lane sums its 32 elu(k)
//     values per column, shfl_xor(16,32) reduces over lq-lanes, lq==0 writes
//     partial[bx*2+wm][col] (write-once, deterministic). ksum_reduce sums the
//     64 row-groups per batch. Deletes ksum_partial's 64 MB HBM re-read.
// GEMM structure (= round 2, measured 121.5-122.8 us, passed):
//   - 256x256 tile, 8 waves, double-buffered 128 KiB LDS, BK=64.
//   - prefetch-shifted register pipeline: each phase issues next phase's
//     ds_reads then runs 16 independent MFMAs; counted lgkm drains under MFMA.
//   - 2 barriers per K-tile at the boundary: lgkmcnt(0); bar; STG_B(t+2);
//     vmcnt(4); bar. vmcnt never 0 in-loop.
//   - chunk-XOR LDS swizzle (0 conflicts measured).
// Tail prefetches (tiles 48/49) land in-bounds of workspace, never consumed.
//
// Pipeline (ws ~150 MB): split_w, split_hidden -> Hs
//   K: kb = elu(h@Wk)+1 + column partials [EPI 0]; ksum_reduce;
//   Q: sc[t][h] epilogue [EPI 1]; V: over kb [EPI 2];
//   token_lite (z=v*sc, LN -> zn bf16 hi|lo in place);
//   G: gate (zn*gamma+beta)*silu(g) in place [EPI 3]; O: Zs@Wo [EPI 2].
// Fallback (ws < 150 MB): round-4 proven on-the-fly-split path.

typedef unsigned short ushort_t;
typedef unsigned int uint_t;

using short8  = __attribute__((ext_vector_type(8))) short;
using floatx4 = __attribute__((ext_vector_type(4))) float;

#define HDIM  1024
#define T_TOK 16384
#define KSPLIT 3072

__device__ __forceinline__ ushort_t f2bf(float f) {
    uint_t u = __builtin_bit_cast(uint_t, f);
    u = (u + 0x7fff + ((u >> 16) & 1)) >> 16;  // RNE
    return (ushort_t)u;
}
__device__ __forceinline__ float bf2f(ushort_t h) {
    uint_t u = ((uint_t)h) << 16;
    return __builtin_bit_cast(float, u);
}
__device__ __forceinline__ void split2(float f, ushort_t& hi, ushort_t& lo) {
    hi = f2bf(f);
    lo = f2bf(f - bf2f(hi));
}
__device__ __forceinline__ void gload_lds16(const ushort_t* g, ushort_t* l) {
    __builtin_amdgcn_global_load_lds(
        (const __attribute__((address_space(1))) void*)g,
        (__attribute__((address_space(3))) void*)l, 16, 0, 0);
}

// ---------------- weight split+transpose: W[k][n] fp32 -> WT2[n][2048] bf16 hi|lo ----------------
__global__ void split_w(const float* __restrict__ W0, const float* __restrict__ W1,
                        const float* __restrict__ W2, const float* __restrict__ W3,
                        const float* __restrict__ W4, ushort_t* __restrict__ WT2) {
    __shared__ float tile[32][33];
    const int z = blockIdx.z;
    const float* W = (z == 0) ? W0 : (z == 1) ? W1 : (z == 2) ? W2 : (z == 3) ? W3 : W4;
    ushort_t* dst = WT2 + (size_t)z * HDIM * 2048;
    const int n0 = blockIdx.x * 32, k0 = blockIdx.y * 32;
    const int tx = threadIdx.x & 31, ty0 = threadIdx.x >> 5;
#pragma unroll
    for (int s = 0; s < 4; ++s) {
        int ty = ty0 + 8 * s;
        tile[ty][tx] = W[(size_t)(k0 + ty) * HDIM + n0 + tx];
    }
    __syncthreads();
#pragma unroll
    for (int s = 0; s < 4; ++s) {
        int ty = ty0 + 8 * s;
        float v = tile[tx][ty];
        ushort_t hi, lo;
        split2(v, hi, lo);
        dst[(size_t)(n0 + ty) * 2048 + k0 + tx] = hi;
        dst[(size_t)(n0 + ty) * 2048 + 1024 + k0 + tx] = lo;
    }
}

// ---------------- hidden split: h[t][1024] fp32 -> Hs[t][2048] bf16 hi|lo ----------------
__global__ __launch_bounds__(256)
void split_hidden(const float* __restrict__ h, ushort_t* __restrict__ Hs) {
    const int t = blockIdx.x;
    const int c = threadIdx.x;
    const float4 x = ((const float4*)(h + (size_t)t * HDIM))[c];
    ushort_t hi[4], lo[4];
    split2(x.x, hi[0], lo[0]); split2(x.y, hi[1], lo[1]);
    split2(x.z, hi[2], lo[2]); split2(x.w, hi[3], lo[3]);
    ushort_t* row = Hs + (size_t)t * 2048;
    uint2 hp, lp;
    hp.x = (uint_t)hi[0] | ((uint_t)hi[1] << 16);
    hp.y = (uint_t)hi[2] | ((uint_t)hi[3] << 16);
    lp.x = (uint_t)lo[0] | ((uint_t)lo[1] << 16);
    lp.y = (uint_t)lo[2] | ((uint_t)lo[3] << 16);
    *(uint2*)(row + c * 4) = hp;
    *(uint2*)(row + 1024 + c * 4) = lp;
}

// ---------------- 256x256 prefetch-pipelined split GEMM (round-2 proven) ----------------
// EPI 0: D = elu(A@B)+1 fp32 + column partials  EPI 1: sc-reduction (q)
// EPI 2: D = A@B fp32                           EPI 3: gate RMW on zbuf

#define FENCE() asm volatile("" ::: "memory")
#define VMW4()  asm volatile("s_waitcnt vmcnt(4)" ::: "memory")

#define STG_A(t, h, bsel) do { \
    const int ka_ = ((t) * 64 >= 2048) ? ((t) * 64 - 2048) : ((t) * 64); \
    gload_lds16(Ag + (size_t)((h) * 128) * 2048 + ka_, \
                &As[(bsel) * 16384 + ((h) * 128 + w * 16) * 64]); \
    gload_lds16(Ag + (size_t)((h) * 128 + 8) * 2048 + ka_, \
                &As[(bsel) * 16384 + ((h) * 128 + w * 16 + 8) * 64]); \
  } while (0)

#define STG_B(t, h, bsel) do { \
    const int kb_ = ((t) * 64 >= 1024) ? ((t) * 64 - 1024) : ((t) * 64); \
    gload_lds16(Bg + (size_t)((h) * 128) * 2048 + kb_, \
                &Bs[(bsel) * 16384 + ((h) * 128 + w * 16) * 64]); \
    gload_lds16(Bg + (size_t)((h) * 128 + 8) * 2048 + kb_, \
                &Bs[(bsel) * 16384 + ((h) * 128 + w * 16 + 8) * 64]); \
  } while (0)

// af fragment block mb (0 or 4): rows (wm*128 + (mb+i)*16 + lrow); kc chunk.
#define RD_A(dst, bsel, mb, kc) do { \
    const ushort_t* _pa = ((kc) ? Ar1 : Ar0) + (bsel) * 16384; \
    _Pragma("unroll") \
    for (int _i = 0; _i < 4; ++_i) \
        dst[_i] = *(const short8*)(_pa + ((mb) + _i) * 1024); \
  } while (0)

#define RD_B(dst, bsel, kc) do { \
    const ushort_t* _pb = ((kc) ? Br1 : Br0) + (bsel) * 16384; \
    _Pragma("unroll") \
    for (int _j = 0; _j < 4; ++_j) \
        dst[_j] = *(const short8*)(_pb + _j * 1024); \
  } while (0)

// 16 independent MFMAs: acc[mb..mb+3][0..3] += a[i] x b[j]  (one k-chunk)
#define MMX(mb, a, b) do { \
    __builtin_amdgcn_s_setprio(1); \
    _Pragma("unroll") \
    for (int _i = 0; _i < 4; ++_i) \
    _Pragma("unroll") \
    for (int _j = 0; _j < 4; ++_j) \
        acc[(mb) + _i][_j] = __builtin_amdgcn_mfma_f32_16x16x32_bf16( \
            a[_i], b[_j], acc[(mb) + _i][_j], 0, 0, 0); \
    __builtin_amdgcn_s_setprio(0); \
  } while (0)

// One K-tile. Entry invariant: afA = af(t)[m0-3][k0], bfv0 = bf(t)[k0],
// both landed. Reads for phase p+1 issue before MMX(p) and drain under it.
#define TILE(t, bsel) do { \
    /* p0: k0 x m0-3 */ \
    RD_A(afB, bsel, 4, 0); \
    STG_A((t) + 1, 0, (bsel) ^ 1); STG_A((t) + 1, 1, (bsel) ^ 1); \
    MMX(0, afA, bfv0); \
    /* p1: k0 x m4-7 */ \
    RD_A(afA, bsel, 0, 1); \
    RD_B(bfv1, bsel, 1); \
    MMX(4, afB, bfv0); \
    /* p2: k1 x m0-3 */ \
    RD_A(afB, bsel, 4, 1); \
    MMX(0, afA, bfv1); \
    /* tile boundary: drain reads; bar; stage B(t+2); counted vmcnt; bar */ \
    __builtin_amdgcn_sched_barrier(0); \
    asm volatile("s_waitcnt lgkmcnt(0)" ::: "memory"); \
    FENCE(); __builtin_amdgcn_s_barrier(); FENCE(); \
    STG_B((t) + 2, 0, bsel); STG_B((t) + 2, 1, bsel); \
    VMW4(); \
    FENCE(); __builtin_amdgcn_s_barrier(); FENCE(); \
    __builtin_amdgcn_sched_barrier(0); \
    /* p3: k1 x m4-7, prefetch tile t+1 phase-0 frags */ \
    RD_A(afA, (bsel) ^ 1, 0, 0); \
    RD_B(bfv0, (bsel) ^ 1, 0); \
    MMX(4, afB, bfv1); \
  } while (0)

template <int EPI>
__global__ __launch_bounds__(512, 2)
void gemm256(const ushort_t* __restrict__ A, const ushort_t* __restrict__ Bw,
             float* __restrict__ D, const float* __restrict__ kf,
             const float* __restrict__ ksum, float* __restrict__ scbuf,
             ushort_t* __restrict__ zbuf, const float* __restrict__ gamma,
             const float* __restrict__ beta, float* __restrict__ partial) {
    __shared__ ushort_t As[2 * 256 * 64];   // 64 KiB
    __shared__ ushort_t Bs[2 * 256 * 64];   // 64 KiB
    const int tid = threadIdx.x;
    const int bx = blockIdx.x, by = blockIdx.y;
    const int w = tid >> 6, lane = tid & 63;
    const int wm = w & 1, wn = w >> 1;          // 2 M-waves x 4 N-waves
    const int lrow = lane & 15, lq = lane >> 4;

    // staging: wave w covers rows h*128 + w*16 + {0..15}; lane covers row
    // +(lane>>3), swizzled 16B chunk ((lane&7) ^ (row&7)).
    const int srow = lane >> 3;
    const int scol = ((lane & 7) ^ srow) * 8;
    const ushort_t* Ag = A + (size_t)(bx * 256 + w * 16 + srow) * 2048 + scol;
    const ushort_t* Bg = Bw + (size_t)(by * 256 + w * 16 + srow) * 2048 + scol;

    // read-side unswizzle bases (kk=0 chunk c0, kk=32 chunk c1)
    const int c0 = (lq ^ (lrow & 7)) * 8;
    const int c1 = ((lq + 4) ^ (lrow & 7)) * 8;
    const ushort_t* Ar0 = As + (wm * 128 + lrow) * 64 + c0;
    const ushort_t* Ar1 = As + (wm * 128 + lrow) * 64 + c1;
    const ushort_t* Br0 = Bs + (wn * 64 + lrow) * 64 + c0;
    const ushort_t* Br1 = Bs + (wn * 64 + lrow) * 64 + c1;

    floatx4 acc[8][4] = {};
    short8 afA[4], afB[4], bfv0[4], bfv1[4];

    // prologue: tile 0 (A,B) + B(1); vmcnt(4) -> tile 0 landed, B(1) in flight
    STG_A(0, 0, 0); STG_A(0, 1, 0);
    STG_B(0, 0, 0); STG_B(0, 1, 0);
    STG_B(1, 0, 1); STG_B(1, 1, 1);
    VMW4();
    FENCE(); __builtin_amdgcn_s_barrier(); FENCE();
    __builtin_amdgcn_sched_barrier(0);
    RD_A(afA, 0, 0, 0);
    RD_B(bfv0, 0, 0);

#pragma unroll 1
    for (int t = 0; t < 48; t += 2) {
        TILE(t, 0);
        TILE(t + 1, 1);
    }

    const int rowbase = bx * 256 + wm * 128 + lq * 4;
    const int colbase = by * 256 + wn * 64 + lrow;

    if constexpr (EPI == 0) {
        // K epilogue: D = elu(acc)+1, plus fused column partial sums.
        // Lane sums its 32 values per j; shfl_xor(16,32) reduces over lq;
        // lq==0 writes partial[(bx*2+wm)][col] once (deterministic).
        float s[4] = {0.f, 0.f, 0.f, 0.f};
#pragma unroll
        for (int i = 0; i < 8; ++i)
#pragma unroll
            for (int j = 0; j < 4; ++j) {
                const int col = colbase + j * 16;
#pragma unroll
                for (int r = 0; r < 4; ++r) {
                    const int row = rowbase + i * 16 + r;
                    float val = acc[i][j][r];
                    val = (val > 0.0f) ? (val + 1.0f) : (expm1f(val) + 1.0f);
                    s[j] += val;
                    D[(size_t)row * HDIM + col] = val;
                }
            }
#pragma unroll
        for (int j = 0; j < 4; ++j) {
            s[j] += __shfl_xor(s[j], 16, 64);
            s[j] += __shfl_xor(s[j], 32, 64);
        }
        if (lq == 0) {
            const int g = bx * 2 + wm;   // 128-row group id (0..127)
#pragma unroll
            for (int j = 0; j < 4; ++j)
                partial[(size_t)g * HDIM + colbase + j * 16] = s[j];
        }
    } else if constexpr (EPI == 2) {
#pragma unroll
        for (int i = 0; i < 8; ++i)
#pragma unroll
            for (int j = 0; j < 4; ++j) {
                const int col = colbase + j * 16;
#pragma unroll
                for (int r = 0; r < 4; ++r) {
                    const int row = rowbase + i * 16 + r;
                    D[(size_t)row * HDIM + col] = acc[i][j][r];
                }
            }
    } else if constexpr (EPI == 1) {
        // q epilogue: head h = by*4 + wn spans cols [h*64, h*64+64)
        const int b = bx >> 5;  // uniform per block (row/8192)
        float ksv[4];
#pragma unroll
        for (int j = 0; j < 4; ++j) ksv[j] = ksum[b * HDIM + colbase + j * 16];
        const int h = by * 4 + wn;
#pragma unroll
        for (int i = 0; i < 8; ++i)
#pragma unroll
            for (int r = 0; r < 4; ++r) {
                const int row = rowbase + i * 16 + r;
                float qk = 0.f, nm = 0.f;
#pragma unroll
                for (int j = 0; j < 4; ++j) {
                    float qv = acc[i][j][r];
                    qv = (qv > 0.0f) ? (qv + 1.0f) : (expm1f(qv) + 1.0f);
                    const float kv = kf[(size_t)row * HDIM + colbase + j * 16];
                    qk += qv * kv;
                    nm += qv * ksv[j];
                }
#pragma unroll
                for (int off = 1; off < 16; off <<= 1) {
                    qk += __shfl_xor(qk, off, 64);
                    nm += __shfl_xor(nm, off, 64);
                }
                if (lrow == 0) scbuf[row * 16 + h] = qk / (nm + 1e-6f);
            }
    } else {  // EPI == 3: gate zn' = (zn*gamma+beta)*silu(g), in-place RMW
#pragma unroll
        for (int i = 0; i < 8; ++i)
#pragma unroll
            for (int j = 0; j < 4; ++j) {
                const int col = colbase + j * 16;
                const float gam = gamma[col], bet = beta[col];
#pragma unroll
                for (int r = 0; r < 4; ++r) {
                    const int row = rowbase + i * 16 + r;
                    ushort_t* zr = zbuf + (size_t)row * 2048;
                    const float zn = bf2f(zr[col]) + bf2f(zr[1024 + col]);
                    const float g = acc[i][j][r];
                    const float sg = g / (1.0f + expf(-g));
                    ushort_t hi, lo;
                    split2((zn * gam + bet) * sg, hi, lo);
                    zr[col] = hi;
                    zr[1024 + col] = lo;
                }
            }
    }
}

// ---------------- swizzled m97-style 128x128 split GEMM (fallback O-GEMM) ----------------
template <int EPI>
__global__ __launch_bounds__(256)
void gemm_swz(const ushort_t* __restrict__ A, const ushort_t* __restrict__ Bw,
              float* __restrict__ D, const float* __restrict__ kf,
              const float* __restrict__ ksum, float* __restrict__ scbuf,
              ushort_t* __restrict__ zbuf) {
    __shared__ ushort_t As[128 * 64];
    __shared__ ushort_t Bs[128 * 64];
    const int tid = threadIdx.x;
    const int bx = blockIdx.x, by = blockIdx.y;
    const int w = tid >> 6, lane = tid & 63;
    const int wm = w & 1, wn = w >> 1;
    const int lrow = lane & 15, lq = lane >> 4;

    const int srow = lane >> 3;
    const int scol = ((lane & 7) ^ srow) * 8;
    const ushort_t* Ag = A + (size_t)(bx * 128 + w * 32 + srow) * 2048 + scol;
    const ushort_t* Bg = Bw + (size_t)(by * 128 + w * 32 + srow) * 2048 + scol;

    floatx4 acc[4][4] = {};

    for (int k0 = 0; k0 < KSPLIT; k0 += 64) {
        const int ka = k0 - ((k0 >= 2048) ? 2048 : 0);
        const int kb = k0 - ((k0 >= 1024) ? 1024 : 0);
        __syncthreads();
#pragma unroll
        for (int n = 0; n < 4; ++n) {
            gload_lds16(Ag + (size_t)(n * 8) * 2048 + ka, &As[(w * 32 + n * 8) * 64]);
            gload_lds16(Bg + (size_t)(n * 8) * 2048 + kb, &Bs[(w * 32 + n * 8) * 64]);
        }
        __syncthreads();
#pragma unroll
        for (int kk = 0; kk < 64; kk += 32) {
            short8 af[4], bf[4];
#pragma unroll
            for (int i = 0; i < 4; ++i) {
                const int c = (((kk >> 3) + lq) ^ (lrow & 7)) * 8;
                af[i] = *(const short8*)&As[(wm * 64 + i * 16 + lrow) * 64 + c];
            }
#pragma unroll
            for (int j = 0; j < 4; ++j) {
                const int c = (((kk >> 3) + lq) ^ (lrow & 7)) * 8;
                bf[j] = *(const short8*)&Bs[(wn * 64 + j * 16 + lrow) * 64 + c];
            }
#pragma unroll
            for (int i = 0; i < 4; ++i)
#pragma unroll
                for (int j = 0; j < 4; ++j)
                    acc[i][j] = __builtin_amdgcn_mfma_f32_16x16x32_bf16(af[i], bf[j], acc[i][j], 0, 0, 0);
        }
    }

    const int rowbase = bx * 128 + wm * 64 + lq * 4;
    const int colbase = by * 128 + wn * 64 + lrow;
#pragma unroll
    for (int i = 0; i < 4; ++i)
#pragma unroll
        for (int j = 0; j < 4; ++j) {
            const int col = colbase + j * 16;
#pragma unroll
            for (int r = 0; r < 4; ++r) {
                const int row = rowbase + i * 16 + r;
                float val = acc[i][j][r];
                if (EPI == 0) val = (val > 0.0f) ? (val + 1.0f) : (expm1f(val) + 1.0f);
                D[(size_t)row * HDIM + col] = val;
            }
        }
}

// ---------------- ksum: stage-2 reduce over 128-row-group partials ----------------
__global__ void ksum_partial(const float* __restrict__ kf, float* __restrict__ partial) {
    const int rg = blockIdx.x;
    const int tid = threadIdx.x;
    const float4* p = (const float4*)(kf + (size_t)rg * 64 * HDIM) + tid;
    float4 s = {0.f, 0.f, 0.f, 0.f};
    for (int r = 0; r < 64; ++r) {
        float4 x = p[(size_t)r * (HDIM / 4)];
        s.x += x.x; s.y += x.y; s.z += x.z; s.w += x.w;
    }
    ((float4*)(partial + (size_t)rg * HDIM))[tid] = s;
}
// NG = row-groups per batch (main path: 64 groups of 128 rows; fallback: 128 of 64)
template <int NG>
__global__ void ksum_reduce(const float* __restrict__ partial, float* __restrict__ ksum) {
    const int b = blockIdx.y;
    const int c = blockIdx.x * 256 + threadIdx.x;
    float s = 0.f;
    const float* p = partial + (size_t)b * NG * HDIM + c;
    for (int rg = 0; rg < NG; ++rg) s += p[(size_t)rg * HDIM];
    ksum[b * HDIM + c] = s;
}

// ---------------- token-lite: z = v*sc, LayerNorm -> zn bf16 hi|lo in place ----------------
__global__ __launch_bounds__(256)
void token_lite(float* vz, const float* __restrict__ scbuf) {
    const int t = blockIdx.x;
    const int tid = threadIdx.x;
    const float4 v = ((const float4*)(vz + (size_t)t * HDIM))[tid];
    const float sc = scbuf[t * 16 + (tid >> 4)];
    float z[4] = {v.x * sc, v.y * sc, v.z * sc, v.w * sc};

    __shared__ float red[8];
    const int wv = tid >> 6, lane = tid & 63;

    float s1 = z[0] + z[1] + z[2] + z[3];
#pragma unroll
    for (int off = 1; off < 64; off <<= 1) s1 += __shfl_xor(s1, off, 64);
    if (lane == 0) red[wv] = s1;
    __syncthreads();
    const float mu = (red[0] + red[1] + red[2] + red[3]) * (1.0f / 1024.0f);

    float d[4] = {z[0] - mu, z[1] - mu, z[2] - mu, z[3] - mu};
    float s2 = d[0] * d[0] + d[1] * d[1] + d[2] * d[2] + d[3] * d[3];
#pragma unroll
    for (int off = 1; off < 64; off <<= 1) s2 += __shfl_xor(s2, off, 64);
    __syncthreads();
    if (lane == 0) red[4 + wv] = s2;
    __syncthreads();
    const float var = (red[4] + red[5] + red[6] + red[7]) * (1.0f / 1024.0f);
    const float rstd = rsqrtf(var + 1e-5f);

    ushort_t* zrow = (ushort_t*)(vz + (size_t)t * HDIM);
    ushort_t hi[4], lo[4];
#pragma unroll
    for (int c = 0; c < 4; ++c) split2(d[c] * rstd, hi[c], lo[c]);
    uint2 hp, lp;
    hp.x = (uint_t)hi[0] | ((uint_t)hi[1] << 16);
    hp.y = (uint_t)hi[2] | ((uint_t)hi[3] << 16);
    lp.x = (uint_t)lo[0] | ((uint_t)lo[1] << 16);
    lp.y = (uint_t)lo[2] | ((uint_t)lo[3] << 16);
    *(uint2*)(zrow + tid * 4) = hp;
    *(uint2*)(zrow + 1024 + tid * 4) = lp;
}

// ---------------- fallback (ws < 150 MB): round-4 proven on-the-fly-split path ----------------
template <int VAR>
__global__ __launch_bounds__(256, 2)
void gemm_split(const float* __restrict__ A,
                const ushort_t* __restrict__ B0, const ushort_t* __restrict__ B1,
                const ushort_t* __restrict__ B2,
                float* __restrict__ D0, float* __restrict__ D1, float* __restrict__ D2,
                int K) {
    __shared__ ushort_t Ah[128 * 72];
    __shared__ ushort_t Al[128 * 72];
    __shared__ ushort_t Bh[128 * 72];
    __shared__ ushort_t Bl[128 * 72];
    const int tid = threadIdx.x;
    const int bx = blockIdx.x, by = blockIdx.y;
    const ushort_t* Bt;
    float* D;
    int n0;
    bool act;
    if (VAR == 1) {
        const int wsel = by >> 3;
        Bt = (wsel == 0) ? B0 : (wsel == 1) ? B1 : B2;
        D = (wsel == 0) ? D0 : (wsel == 1) ? D1 : D2;
        n0 = (by & 7) * 128;
        act = (wsel == 0);
    } else {
        Bt = B0; D = D0; n0 = by * 128; act = true;
    }
    const int w = tid >> 6, lane = tid & 63;
    const int wm = w & 1, wn = w >> 1;
    const int lrow = lane & 15, lq = lane >> 4;
    const int srow = tid >> 1;
    const int shalf = (tid & 1) * 32;
    const float* Arow = A + (size_t)(bx * 128 + srow) * K;
    const ushort_t* Brow = Bt + (size_t)(n0 + srow) * 2048;
    floatx4 acc[4][4] = {};
    for (int k0 = 0; k0 < K; k0 += 64) {
        float4 afr[8];
        uint4 bhr[4], blr[4];
#pragma unroll
        for (int g = 0; g < 4; ++g) {
            afr[2 * g]     = *(const float4*)(Arow + k0 + shalf + g * 8);
            afr[2 * g + 1] = *(const float4*)(Arow + k0 + shalf + g * 8 + 4);
            bhr[g] = *(const uint4*)(Brow + k0 + shalf + g * 8);
            blr[g] = *(const uint4*)(Brow + 1024 + k0 + shalf + g * 8);
        }
        __syncthreads();
#pragma unroll
        for (int g = 0; g < 4; ++g) {
            ushort_t h[8], l[8];
            const float4 f0 = afr[2 * g], f1 = afr[2 * g + 1];
            split2(f0.x, h[0], l[0]); split2(f0.y, h[1], l[1]);
            split2(f0.z, h[2], l[2]); split2(f0.w, h[3], l[3]);
            split2(f1.x, h[4], l[4]); split2(f1.y, h[5], l[5]);
            split2(f1.z, h[6], l[6]); split2(f1.w, h[7], l[7]);
            uint4 hp, lp;
            hp.x = (uint_t)h[0] | ((uint_t)h[1] << 16);
            hp.y = (uint_t)h[2] | ((uint_t)h[3] << 16);
            hp.z = (uint_t)h[4] | ((uint_t)h[5] << 16);
            hp.w = (uint_t)h[6] | ((uint_t)h[7] << 16);
            lp.x = (uint_t)l[0] | ((uint_t)l[1] << 16);
            lp.y = (uint_t)l[2] | ((uint_t)l[3] << 16);
            lp.z = (uint_t)l[4] | ((uint_t)l[5] << 16);
            lp.w = (uint_t)l[6] | ((uint_t)l[7] << 16);
            *(uint4*)&Ah[srow * 72 + shalf + g * 8] = hp;
            *(uint4*)&Al[srow * 72 + shalf + g * 8] = lp;
            *(uint4*)&Bh[srow * 72 + shalf + g * 8] = bhr[g];
            *(uint4*)&Bl[srow * 72 + shalf + g * 8] = blr[g];
        }
        __syncthreads();
#pragma unroll
        for (int kk = 0; kk < 64; kk += 32) {
            short8 ah[4], bh[4], xl[4];
#pragma unroll
            for (int i = 0; i < 4; ++i)
                ah[i] = *(const short8*)&Ah[(wm * 64 + i * 16 + lrow) * 72 + kk + lq * 8];
#pragma unroll
            for (int j = 0; j < 4; ++j)
                bh[j] = *(const short8*)&Bh[(wn * 64 + j * 16 + lrow) * 72 + kk + lq * 8];
#pragma unroll
            for (int i = 0; i < 4; ++i)
#pragma unroll
                for (int j = 0; j < 4; ++j)
                    acc[i][j] = __builtin_amdgcn_mfma_f32_16x16x32_bf16(ah[i], bh[j], acc[i][j], 0, 0, 0);
#pragma unroll
            for (int i = 0; i < 4; ++i)
                xl[i] = *(const short8*)&Al[(wm * 64 + i * 16 + lrow) * 72 + kk + lq * 8];
#pragma unroll
            for (int i = 0; i < 4; ++i)
#pragma unroll
                for (int j = 0; j < 4; ++j)
                    acc[i][j] = __builtin_amdgcn_mfma_f32_16x16x32_bf16(xl[i], bh[j], acc[i][j], 0, 0, 0);
#pragma unroll
            for (int j = 0; j < 4; ++j)
                xl[j] = *(const short8*)&Bl[(wn * 64 + j * 16 + lrow) * 72 + kk + lq * 8];
#pragma unroll
            for (int i = 0; i < 4; ++i)
#pragma unroll
                for (int j = 0; j < 4; ++j)
                    acc[i][j] = __builtin_amdgcn_mfma_f32_16x16x32_bf16(ah[i], xl[j], acc[i][j], 0, 0, 0);
        }
    }
    const int rowbase = bx * 128 + wm * 64 + lq * 4;
    const int colbase = n0 + wn * 64 + lrow;
#pragma unroll
    for (int i = 0; i < 4; ++i)
#pragma unroll
        for (int j = 0; j < 4; ++j) {
            const int col = colbase + j * 16;
#pragma unroll
            for (int r = 0; r < 4; ++r) {
                const int row = rowbase + i * 16 + r;
                float val = acc[i][j][r];
                if (act) val = (val > 0.0f) ? (val + 1.0f) : (expm1f(val) + 1.0f);
                D[(size_t)row * HDIM + col] = val;
            }
        }
}

__global__ __launch_bounds__(256)
void token_f32(const float* __restrict__ qd, const float* __restrict__ vd,
               const float* __restrict__ gd, float* kz,
               const float* __restrict__ ksum,
               const float* __restrict__ gamma, const float* __restrict__ beta,
               int chunk_base) {
    const int tl = blockIdx.x;
    const int t = chunk_base + tl;
    const int b = t >> 13;
    const int tid = threadIdx.x;
    const float4 q = ((const float4*)(qd + (size_t)tl * HDIM))[tid];
    const float4 k = ((const float4*)(kz + (size_t)t * HDIM))[tid];
    const float4 v = ((const float4*)(vd + (size_t)tl * HDIM))[tid];
    const float4 ks = ((const float4*)(ksum + (size_t)b * HDIM))[tid];
    float qk = q.x * k.x + q.y * k.y + q.z * k.z + q.w * k.w;
    float nm = q.x * ks.x + q.y * ks.y + q.z * ks.z + q.w * ks.w;
#pragma unroll
    for (int off = 1; off < 16; off <<= 1) {
        qk += __shfl_xor(qk, off, 64);
        nm += __shfl_xor(nm, off, 64);
    }
    const float sc = qk / (nm + 1e-6f);
    float z[4] = {v.x * sc, v.y * sc, v.z * sc, v.w * sc};
    __shared__ float red[8];
    const int wv = tid >> 6, lane = tid & 63;
    float s1 = z[0] + z[1] + z[2] + z[3];
#pragma unroll
    for (int off = 1; off < 64; off <<= 1) s1 += __shfl_xor(s1, off, 64);
    if (lane == 0) red[wv] = s1;
    __syncthreads();
    const float mu = (red[0] + red[1] + red[2] + red[3]) * (1.0f / 1024.0f);
    float d[4] = {z[0] - mu, z[1] - mu, z[2] - mu, z[3] - mu};
    float s2 = d[0] * d[0] + d[1] * d[1] + d[2] * d[2] + d[3] * d[3];
#pragma unroll
    for (int off = 1; off < 64; off <<= 1) s2 += __shfl_xor(s2, off, 64);
    __syncthreads();
    if (lane == 0) red[4 + wv] = s2;
    __syncthreads();
    const float var = (red[4] + red[5] + red[6] + red[7]) * (1.0f / 1024.0f);
    const float rstd = rsqrtf(var + 1e-5f);
    const float4 gm = ((const float4*)gamma)[tid];
    const float4 bt = ((const float4*)beta)[tid];
    const float4 g = ((const float4*)(gd + (size_t)tl * HDIM))[tid];
    const float gv[4] = {g.x, g.y, g.z, g.w};
    const float gmv[4] = {gm.x, gm.y, gm.z, gm.w};
    const float btv[4] = {bt.x, bt.y, bt.z, bt.w};
    ushort_t hi[4], lo[4];
#pragma unroll
    for (int c = 0; c < 4; ++c) {
        const float zn = d[c] * rstd * gmv[c] + btv[c];
        const float sg = gv[c] / (1.0f + expf(-gv[c]));
        split2(zn * sg, hi[c], lo[c]);
    }
    ushort_t* zrow = (ushort_t*)(kz + (size_t)t * HDIM);
    uint2 hp, lp;
    hp.x = (uint_t)hi[0] | ((uint_t)hi[1] << 16);
    hp.y = (uint_t)hi[2] | ((uint_t)hi[3] << 16);
    lp.x = (uint_t)lo[0] | ((uint_t)lo[1] << 16);
    lp.y = (uint_t)lo[2] | ((uint_t)lo[3] << 16);
    *(uint2*)(zrow + tid * 4) = hp;
    *(uint2*)(zrow + 1024 + tid * 4) = lp;
}

// ---------------- launcher ----------------
extern "C" void kernel_launch(void* const* d_in, const int* in_sizes, int n_in,
                              void* d_out, int out_size, void* d_ws, size_t ws_size,
                              hipStream_t stream) {
    const float* hidden = (const float*)d_in[0];
    const float* Wq = (const float*)d_in[1];
    const float* Wk = (const float*)d_in[2];
    const float* Wv = (const float*)d_in[3];
    const float* Wg = (const float*)d_in[4];
    const float* Wo = (const float*)d_in[5];
    const float* gamma = (const float*)d_in[6];
    const float* beta = (const float*)d_in[7];

    char* w = (char*)d_ws;
    float* kb = (float*)w;            w += (size_t)67108864;   // k -> v -> zn -> Zs
    ushort_t* WT2 = (ushort_t*)w;     w += (size_t)20971520;   // 5 weights split [n][2048]
    float* partial = (float*)w;       w += (size_t)1048576;
    float* ksum = (float*)w;          w += (size_t)8192;
    float* scbuf = (float*)w;         w += (size_t)1048576;    // sc[t][16]
    const size_t base = (size_t)(w - (char*)d_ws);             // ~90.2 MB

    ushort_t* Wk2 = WT2;
    ushort_t* Wq2 = WT2 + (size_t)1 * HDIM * 2048;
    ushort_t* Wv2 = WT2 + (size_t)2 * HDIM * 2048;
    ushort_t* Wg2 = WT2 + (size_t)3 * HDIM * 2048;
    ushort_t* Wo2 = WT2 + (size_t)4 * HDIM * 2048;

    split_w<<<dim3(32, 32, 5), 256, 0, stream>>>(Wk, Wq, Wv, Wg, Wo, WT2);

    if (ws_size >= base + 67108864ull) {  // main path (measured ws >= ~173 MB)
        ushort_t* Hs = (ushort_t*)w;
        split_hidden<<<dim3(T_TOK), 256, 0, stream>>>(hidden, Hs);
        // K: kb = elu(h@Wk)+1, fused column partials -> partial[128][1024]
        gemm256<0><<<dim3(64, 4), 512, 0, stream>>>(Hs, Wk2, kb, nullptr, nullptr,
                                                    nullptr, nullptr, nullptr, nullptr,
                                                    partial);
        ksum_reduce<64><<<dim3(4, 2), 256, 0, stream>>>(partial, ksum);
        // Q: epilogue-reduce sc[t][h]
        gemm256<1><<<dim3(64, 4), 512, 0, stream>>>(Hs, Wq2, nullptr, kb, ksum,
                                                    scbuf, nullptr, nullptr, nullptr,
                                                    nullptr);
        // V: v over kb (k dead)
        gemm256<2><<<dim3(64, 4), 512, 0, stream>>>(Hs, Wv2, kb, nullptr, nullptr,
                                                    nullptr, nullptr, nullptr, nullptr,
                                                    nullptr);
        // token-lite: z=v*sc, LN -> zn hi|lo in place
        token_lite<<<dim3(T_TOK), 256, 0, stream>>>(kb, scbuf);
        // G: gate (zn*gamma+beta)*silu(g) in place
        gemm256<3><<<dim3(64, 4), 512, 0, stream>>>(Hs, Wg2, nullptr, nullptr, nullptr,
                                                    nullptr, (ushort_t*)kb, gamma, beta,
                                                    nullptr);
        // O: out = Zs @ Wo
        gemm256<2><<<dim3(64, 4), 512, 0, stream>>>((const ushort_t*)kb, Wo2,
                                                    (float*)d_out, nullptr, nullptr,
                                                    nullptr, nullptr, nullptr, nullptr,
                                                    nullptr);
    } else {  // fallback: round-4 proven path (~110 MB)
        const int C = 2048;
        float* qc = (float*)w;
        float* vc = qc + (size_t)C * HDIM;
        float* gc = vc + (size_t)C * HDIM;
        gemm_split<0><<<dim3(128, 8), 256, 0, stream>>>(hidden, Wk2, nullptr, nullptr,
                                                        kb, nullptr, nullptr, HDIM);
        ksum_partial<<<dim3(256), 256, 0, stream>>>(kb, partial);
        ksum_reduce<128><<<dim3(4, 2), 256, 0, stream>>>(partial, ksum);
        for (int c = 0; c < 8; ++c) {
            const float* Ac = hidden + (size_t)c * C * HDIM;
            gemm_split<1><<<dim3(C / 128, 24), 256, 0, stream>>>(Ac, Wq2, Wv2, Wg2,
                                                                 qc, vc, gc, HDIM);
            token_f32<<<dim3(C), 256, 0, stream>>>(qc, vc, gc, kb, ksum,
                                                   gamma, beta, c * C);
        }
        gemm_swz<2><<<dim3(128, 8), 256, 0, stream>>>((const ushort_t*)kb, Wo2,
                                                      (float*)d_out, nullptr, nullptr,
                                                      nullptr, nullptr);
    }
}